// Round 1
// baseline (1180.331 us; speedup 1.0000x reference)
//
#include <hip/hip_runtime.h>
#include <cmath>

#define NFEAT_IN 128
#define NFEAT_H 64
#define BN_EPS 1e-5f

__global__ __launch_bounds__(256) void deg_kernel(const int* __restrict__ src,
                                                  const int* __restrict__ dst,
                                                  float* __restrict__ deg_out,
                                                  float* __restrict__ deg_in, int E) {
    int i = blockIdx.x * 256 + threadIdx.x;
    if (i < E) {
        atomicAdd(&deg_out[src[i]], 1.0f);
        atomicAdd(&deg_in[dst[i]], 1.0f);
    }
}

// in-place: deg -> rsqrt(max(deg,1))
__global__ __launch_bounds__(256) void norm_kernel(float* __restrict__ deg, int n2) {
    int i = blockIdx.x * 256 + threadIdx.x;
    if (i < n2) {
        deg[i] = rsqrtf(fmaxf(deg[i], 1.0f));
    }
}

// out[row][f] = sum_k (x[row][k]*norm[row]) * W[k][f]   (64 out feats)
template <int K>
__global__ __launch_bounds__(256) void gemm_kernel(const float* __restrict__ x,
                                                   const float* __restrict__ norm,
                                                   const float* __restrict__ W,
                                                   float* __restrict__ out, int n) {
    __shared__ float sW[K * 64];
    __shared__ float sx[4][K];
    int tid = threadIdx.x;
    int f = tid & 63;
    int r = tid >> 6;
    for (int i = tid; i < K * 64; i += 256) sW[i] = W[i];
    int row0 = blockIdx.x * 4;
    for (int rr = 0; rr < 4; ++rr) {
        int row = row0 + rr;
        if (row < n) {
            float nv = norm[row];
            for (int k = tid; k < K; k += 256)
                sx[rr][k] = x[(long long)row * K + k] * nv;
        }
    }
    __syncthreads();
    int row = row0 + r;
    if (row >= n) return;
    float acc = 0.f;
#pragma unroll
    for (int k = 0; k < K; ++k) acc = fmaf(sx[r][k], sW[k * 64 + f], acc);
    out[(long long)row * 64 + f] = acc;
}

// agg[dst[e]][f] += h[src[e]][f]
__global__ __launch_bounds__(256) void scatter_kernel(const float* __restrict__ h,
                                                      const int* __restrict__ src,
                                                      const int* __restrict__ dst,
                                                      float* __restrict__ agg, int E) {
    long long idx = (long long)blockIdx.x * 256 + threadIdx.x;
    int e = (int)(idx >> 6);
    if (e >= E) return;
    int f = (int)(idx & 63);
    int s = src[e];
    int d = dst[e];
    atomicAdd(&agg[(long long)d * 64 + f], h[(long long)s * 64 + f]);
}

// in-place: hb = elu(hb*norm_dst + bias); accumulate sum/sumsq per feature into stats
__global__ __launch_bounds__(256) void elu_stats_kernel(float* __restrict__ hb,
                                                        const float* __restrict__ normd,
                                                        const float* __restrict__ bias,
                                                        float* __restrict__ stats, int n) {
    int tid = threadIdx.x;
    int f = tid & 63;
    int rr = tid >> 6;
    float b = bias[f];
    float sum = 0.f, sq = 0.f;
    for (int row = blockIdx.x * 4 + rr; row < n; row += gridDim.x * 4) {
        long long i = (long long)row * 64 + f;
        float v = hb[i] * normd[row] + b;
        v = v > 0.f ? v : expm1f(v);
        hb[i] = v;
        sum += v;
        sq += v * v;
    }
    __shared__ float ssum[256], ssq[256];
    ssum[tid] = sum;
    ssq[tid] = sq;
    __syncthreads();
    if (tid < 64) {
        sum = ssum[tid] + ssum[tid + 64] + ssum[tid + 128] + ssum[tid + 192];
        sq = ssq[tid] + ssq[tid + 64] + ssq[tid + 128] + ssq[tid + 192];
        atomicAdd(&stats[tid], sum);
        atomicAdd(&stats[64 + tid], sq);
    }
}

// coef[f] = gamma*inv_std ; coef[64+f] = beta - mean*gamma*inv_std
__global__ __launch_bounds__(64) void bn_finalize(const float* __restrict__ stats,
                                                  const float* __restrict__ gamma,
                                                  const float* __restrict__ beta,
                                                  float* __restrict__ coef, float inv_n) {
    int f = threadIdx.x;
    float mean = stats[f] * inv_n;
    float var = stats[64 + f] * inv_n - mean * mean;
    float a = gamma[f] * rsqrtf(var + BN_EPS);
    coef[f] = a;
    coef[64 + f] = beta[f] - mean * a;
}

__global__ __launch_bounds__(256) void bn_apply(const float* __restrict__ in,
                                                const float* __restrict__ coef,
                                                float* __restrict__ out, long long total) {
    long long i = (long long)blockIdx.x * 256 + threadIdx.x;
    if (i >= total) return;
    int f = (int)(i & 63);
    out[i] = in[i] * coef[f] + coef[64 + f];
}

extern "C" void kernel_launch(void* const* d_in, const int* in_sizes, int n_in,
                              void* d_out, int out_size, void* d_ws, size_t ws_size,
                              hipStream_t stream) {
    const float* features = (const float*)d_in[0];
    const float* W1 = (const float*)d_in[1];
    const float* b1 = (const float*)d_in[2];
    const float* gamma1 = (const float*)d_in[3];
    const float* beta1 = (const float*)d_in[4];
    const float* W2 = (const float*)d_in[5];
    const float* b2 = (const float*)d_in[6];
    const float* gamma2 = (const float*)d_in[7];
    const float* beta2 = (const float*)d_in[8];
    const int* src = (const int*)d_in[9];
    const int* dst = (const int*)d_in[10];
    int N = in_sizes[0] / NFEAT_IN;
    int E = in_sizes[9];

    float* ws = (float*)d_ws;
    float* norm_src = ws;                           // N  (deg_out then norm)
    float* norm_dst = ws + N;                       // N  (deg_in then norm)
    float* bufA = ws + 2LL * N;                     // N*64
    float* bufB = bufA + (long long)N * 64;         // N*64
    float* stats = bufB + (long long)N * 64;        // 128
    float* coef = stats + 128;                      // 128

    float inv_n = 1.0f / (float)N;
    int nblk4 = (N + 3) / 4;
    long long tot = (long long)N * 64;
    int eblk = (int)(((long long)E * 64 + 255) / 256);
    int tblk = (int)((tot + 255) / 256);

    // degree norms
    hipMemsetAsync(norm_src, 0, sizeof(float) * 2LL * N, stream);
    deg_kernel<<<(E + 255) / 256, 256, 0, stream>>>(src, dst, norm_src, norm_dst, E);
    norm_kernel<<<(2 * N + 255) / 256, 256, 0, stream>>>(norm_src, 2 * N);

    // ---- layer 1 ----
    gemm_kernel<NFEAT_IN><<<nblk4, 256, 0, stream>>>(features, norm_src, W1, bufA, N);
    hipMemsetAsync(bufB, 0, sizeof(float) * tot, stream);
    scatter_kernel<<<eblk, 256, 0, stream>>>(bufA, src, dst, bufB, E);
    hipMemsetAsync(stats, 0, sizeof(float) * 128, stream);
    elu_stats_kernel<<<2048, 256, 0, stream>>>(bufB, norm_dst, b1, stats, N);
    bn_finalize<<<1, 64, 0, stream>>>(stats, gamma1, beta1, coef, inv_n);
    bn_apply<<<tblk, 256, 0, stream>>>(bufB, coef, bufA, tot);  // bufA = h1

    // ---- layer 2 ----
    gemm_kernel<NFEAT_H><<<nblk4, 256, 0, stream>>>(bufA, norm_src, W2, bufB, N);
    hipMemsetAsync(bufA, 0, sizeof(float) * tot, stream);
    scatter_kernel<<<eblk, 256, 0, stream>>>(bufB, src, dst, bufA, E);
    hipMemsetAsync(stats, 0, sizeof(float) * 128, stream);
    elu_stats_kernel<<<2048, 256, 0, stream>>>(bufA, norm_dst, b2, stats, N);
    bn_finalize<<<1, 64, 0, stream>>>(stats, gamma2, beta2, coef, inv_n);
    bn_apply<<<tblk, 256, 0, stream>>>(bufA, coef, (float*)d_out, tot);
}

// Round 2
// 712.644 us; speedup vs baseline: 1.6563x; 1.6563x over previous
//
#include <hip/hip_runtime.h>
#include <cmath>

#define NFEAT_IN 128
#define NFEAT_H 64
#define BN_EPS 1e-5f

// ---------------- shared small kernels ----------------

// int degree histogram
__global__ __launch_bounds__(256) void deg_int_kernel(const int* __restrict__ src,
                                                      const int* __restrict__ dst,
                                                      int* __restrict__ deg_s,
                                                      int* __restrict__ deg_d, int E) {
    int i = blockIdx.x * 256 + threadIdx.x;
    if (i < E) {
        atomicAdd(&deg_s[src[i]], 1);
        atomicAdd(&deg_d[dst[i]], 1);
    }
}

// norms from int degrees + segment-grab for dst-grouped edge list.
// NOTE: cursor may alias deg_s (deg_s[i] is read before cursor[i] is written, same thread).
__global__ __launch_bounds__(256) void norm_grab_kernel(const int* __restrict__ deg_s,
                                                        const int* __restrict__ deg_d,
                                                        float* __restrict__ norm_s,
                                                        float* __restrict__ norm_d,
                                                        int* __restrict__ start,
                                                        int* __restrict__ cursor,
                                                        int* __restrict__ counter, int N) {
    int i = blockIdx.x * 256 + threadIdx.x;
    if (i < N) {
        int ds = deg_s[i], dd = deg_d[i];
        norm_s[i] = rsqrtf((float)(ds > 1 ? ds : 1));
        norm_d[i] = rsqrtf((float)(dd > 1 ? dd : 1));
        int st = atomicAdd(counter, dd);
        start[i] = st;
        cursor[i] = st;
    }
}

// group src ids by dst into col[]
__global__ __launch_bounds__(256) void fill_kernel(const int* __restrict__ src,
                                                   const int* __restrict__ dst,
                                                   int* __restrict__ cursor,
                                                   int* __restrict__ col, int E) {
    int e = blockIdx.x * 256 + threadIdx.x;
    if (e < E) {
        int d = dst[e];
        int pos = atomicAdd(&cursor[d], 1);
        col[pos] = src[e];
    }
}

// out[row][f] = sum_k xhat[row][k]*norm[row] * W[k][f]; xhat = FUSE ? x*coef[k]+coef[64+k] : x
template <int K, bool FUSE>
__global__ __launch_bounds__(256) void gemm_kernel(const float* __restrict__ x,
                                                   const float* __restrict__ norm,
                                                   const float* __restrict__ W,
                                                   const float* __restrict__ coef,
                                                   float* __restrict__ out, int n) {
    __shared__ float sW[K * 64];
    __shared__ float sx[4][K];
    int tid = threadIdx.x;
    int f = tid & 63;
    int r = tid >> 6;
    for (int i = tid; i < K * 16; i += 256)
        ((float4*)sW)[i] = ((const float4*)W)[i];
    int row0 = blockIdx.x * 4;
    constexpr int V4 = K / 4;
    for (int i = tid; i < 4 * V4; i += 256) {
        int rr = i / V4, k4 = i - rr * V4;
        int row = row0 + rr;
        if (row < n) {
            float4 v = ((const float4*)(x + (long long)row * K))[k4];
            if (FUSE) {
                int k = k4 * 4;
                v.x = v.x * coef[k] + coef[64 + k];
                v.y = v.y * coef[k + 1] + coef[64 + k + 1];
                v.z = v.z * coef[k + 2] + coef[64 + k + 2];
                v.w = v.w * coef[k + 3] + coef[64 + k + 3];
            }
            float nv = norm[row];
            v.x *= nv; v.y *= nv; v.z *= nv; v.w *= nv;
            ((float4*)sx[rr])[k4] = v;
        }
    }
    __syncthreads();
    int row = row0 + r;
    if (row >= n) return;
    float acc = 0.f;
#pragma unroll
    for (int k = 0; k < K; ++k) acc = fmaf(sx[r][k], sW[k * 64 + f], acc);
    out[(long long)row * 64 + f] = acc;
}

// gather-aggregate per node + norm_dst/bias/ELU + BN stats (fused epilogue)
__global__ __launch_bounds__(256) void agg_fused_kernel(const float* __restrict__ h,
                                                        const int* __restrict__ start,
                                                        const int* __restrict__ degd,
                                                        const int* __restrict__ col,
                                                        const float* __restrict__ normd,
                                                        const float* __restrict__ bias,
                                                        float* __restrict__ out,
                                                        float* __restrict__ stats, int N) {
    int tid = threadIdx.x;
    int f = tid & 63;
    int lr = tid >> 6;
    float b = bias[f];
    float sum = 0.f, sq = 0.f;
    for (int node = blockIdx.x * 4 + lr; node < N; node += gridDim.x * 4) {
        int s0 = start[node];
        int d = degd[node];
        float acc = 0.f;
        int k = 0;
        for (; k + 4 <= d; k += 4) {
            int c0 = col[s0 + k], c1 = col[s0 + k + 1], c2 = col[s0 + k + 2], c3 = col[s0 + k + 3];
            float v0 = h[(long long)c0 * 64 + f];
            float v1 = h[(long long)c1 * 64 + f];
            float v2 = h[(long long)c2 * 64 + f];
            float v3 = h[(long long)c3 * 64 + f];
            acc += v0 + v1 + v2 + v3;
        }
        for (; k < d; ++k) acc += h[(long long)col[s0 + k] * 64 + f];
        float v = acc * normd[node] + b;
        v = v > 0.f ? v : expm1f(v);
        out[(long long)node * 64 + f] = v;
        sum += v;
        sq += v * v;
    }
    __shared__ float ssum[256], ssq[256];
    ssum[tid] = sum;
    ssq[tid] = sq;
    __syncthreads();
    if (tid < 64) {
        sum = ssum[tid] + ssum[tid + 64] + ssum[tid + 128] + ssum[tid + 192];
        sq = ssq[tid] + ssq[tid + 64] + ssq[tid + 128] + ssq[tid + 192];
        atomicAdd(&stats[tid], sum);
        atomicAdd(&stats[64 + tid], sq);
    }
}

__global__ __launch_bounds__(64) void bn_finalize(const float* __restrict__ stats,
                                                  const float* __restrict__ gamma,
                                                  const float* __restrict__ beta,
                                                  float* __restrict__ coef, float inv_n) {
    int f = threadIdx.x;
    float mean = stats[f] * inv_n;
    float var = stats[64 + f] * inv_n - mean * mean;
    float a = gamma[f] * rsqrtf(var + BN_EPS);
    coef[f] = a;
    coef[64 + f] = beta[f] - mean * a;
}

__global__ __launch_bounds__(256) void bn_apply(const float* __restrict__ in,
                                                const float* __restrict__ coef,
                                                float* __restrict__ out, long long total) {
    long long i = (long long)blockIdx.x * 256 + threadIdx.x;
    if (i >= total) return;
    int f = (int)(i & 63);
    out[i] = in[i] * coef[f] + coef[64 + f];
}

// ---------------- fallback (atomic scatter) kernels ----------------

__global__ __launch_bounds__(256) void deg_kernel_f(const int* __restrict__ src,
                                                    const int* __restrict__ dst,
                                                    float* __restrict__ deg_out,
                                                    float* __restrict__ deg_in, int E) {
    int i = blockIdx.x * 256 + threadIdx.x;
    if (i < E) {
        atomicAdd(&deg_out[src[i]], 1.0f);
        atomicAdd(&deg_in[dst[i]], 1.0f);
    }
}

__global__ __launch_bounds__(256) void norm_kernel_f(float* __restrict__ deg, int n2) {
    int i = blockIdx.x * 256 + threadIdx.x;
    if (i < n2) deg[i] = rsqrtf(fmaxf(deg[i], 1.0f));
}

__global__ __launch_bounds__(256) void scatter_kernel(const float* __restrict__ h,
                                                      const int* __restrict__ src,
                                                      const int* __restrict__ dst,
                                                      float* __restrict__ agg, int E) {
    long long idx = (long long)blockIdx.x * 256 + threadIdx.x;
    int e = (int)(idx >> 6);
    if (e >= E) return;
    int f = (int)(idx & 63);
    atomicAdd(&agg[(long long)dst[e] * 64 + f], h[(long long)src[e] * 64 + f]);
}

__global__ __launch_bounds__(256) void elu_stats_kernel(float* __restrict__ hb,
                                                        const float* __restrict__ normd,
                                                        const float* __restrict__ bias,
                                                        float* __restrict__ stats, int n) {
    int tid = threadIdx.x;
    int f = tid & 63;
    int rr = tid >> 6;
    float b = bias[f];
    float sum = 0.f, sq = 0.f;
    for (int row = blockIdx.x * 4 + rr; row < n; row += gridDim.x * 4) {
        long long i = (long long)row * 64 + f;
        float v = hb[i] * normd[row] + b;
        v = v > 0.f ? v : expm1f(v);
        hb[i] = v;
        sum += v;
        sq += v * v;
    }
    __shared__ float ssum[256], ssq[256];
    ssum[tid] = sum;
    ssq[tid] = sq;
    __syncthreads();
    if (tid < 64) {
        sum = ssum[tid] + ssum[tid + 64] + ssum[tid + 128] + ssum[tid + 192];
        sq = ssq[tid] + ssq[tid + 64] + ssq[tid + 128] + ssq[tid + 192];
        atomicAdd(&stats[tid], sum);
        atomicAdd(&stats[64 + tid], sq);
    }
}

// ---------------- launch ----------------

extern "C" void kernel_launch(void* const* d_in, const int* in_sizes, int n_in,
                              void* d_out, int out_size, void* d_ws, size_t ws_size,
                              hipStream_t stream) {
    const float* features = (const float*)d_in[0];
    const float* W1 = (const float*)d_in[1];
    const float* b1 = (const float*)d_in[2];
    const float* gamma1 = (const float*)d_in[3];
    const float* beta1 = (const float*)d_in[4];
    const float* W2 = (const float*)d_in[5];
    const float* b2 = (const float*)d_in[6];
    const float* gamma2 = (const float*)d_in[7];
    const float* beta2 = (const float*)d_in[8];
    const int* src = (const int*)d_in[9];
    const int* dst = (const int*)d_in[10];
    int N = in_sizes[0] / NFEAT_IN;
    int E = in_sizes[9];

    float inv_n = 1.0f / (float)N;
    int nblk4 = (N + 3) / 4;
    long long tot = (long long)N * 64;
    int tblk = (int)((tot + 255) / 256);
    int eblk256 = (E + 255) / 256;
    int nblk256 = (N + 255) / 256;

    // CSR-path workspace layout (ints first, then 16B-aligned floats)
    size_t int_count = (size_t)3 * N + E;                 // deg_s/cursor, deg_d, start, col
    size_t int_total = (int_count + 4 + 3) & ~(size_t)3;  // + counter, pad to 16B
    size_t need = int_total * 4 + ((size_t)2 * N + (size_t)2 * N * 64 + 256) * 4;

    if (ws_size >= need) {
        int* ip = (int*)d_ws;
        int* deg_s = ip;            // later reused as cursor
        int* deg_d = ip + N;
        int* startv = ip + 2LL * N;
        int* col = ip + 3LL * N;
        int* counter = ip + int_count;
        float* fp = (float*)(ip + int_total);
        float* norm_s = fp;
        float* norm_d = fp + N;
        float* bufA = fp + 2LL * N;
        float* bufB = bufA + tot;
        float* stats = bufB + tot;
        float* coef = stats + 128;

        hipMemsetAsync(deg_s, 0, sizeof(int) * 2LL * N, stream);
        hipMemsetAsync(counter, 0, sizeof(int), stream);
        deg_int_kernel<<<eblk256, 256, 0, stream>>>(src, dst, deg_s, deg_d, E);
        norm_grab_kernel<<<nblk256, 256, 0, stream>>>(deg_s, deg_d, norm_s, norm_d,
                                                      startv, /*cursor=*/deg_s, counter, N);
        fill_kernel<<<eblk256, 256, 0, stream>>>(src, dst, /*cursor=*/deg_s, col, E);

        // ---- layer 1 ----
        gemm_kernel<NFEAT_IN, false><<<nblk4, 256, 0, stream>>>(features, norm_s, W1, nullptr, bufA, N);
        hipMemsetAsync(stats, 0, sizeof(float) * 128, stream);
        agg_fused_kernel<<<2048, 256, 0, stream>>>(bufA, startv, deg_d, col, norm_d, b1, bufB, stats, N);
        bn_finalize<<<1, 64, 0, stream>>>(stats, gamma1, beta1, coef, inv_n);

        // ---- layer 2 (BN1 fused into gemm input) ----
        gemm_kernel<NFEAT_H, true><<<nblk4, 256, 0, stream>>>(bufB, norm_s, W2, coef, bufA, N);
        hipMemsetAsync(stats, 0, sizeof(float) * 128, stream);
        agg_fused_kernel<<<2048, 256, 0, stream>>>(bufA, startv, deg_d, col, norm_d, b2, bufB, stats, N);
        bn_finalize<<<1, 64, 0, stream>>>(stats, gamma2, beta2, coef, inv_n);
        bn_apply<<<tblk, 256, 0, stream>>>(bufB, coef, (float*)d_out, tot);
        return;
    }

    // ---------------- fallback: proven atomic-scatter path ----------------
    float* ws = (float*)d_ws;
    float* norm_src = ws;
    float* norm_dst = ws + N;
    float* bufA = ws + 2LL * N;
    float* bufB = bufA + tot;
    float* stats = bufB + tot;
    float* coef = stats + 128;
    int eblk = (int)(((long long)E * 64 + 255) / 256);

    hipMemsetAsync(norm_src, 0, sizeof(float) * 2LL * N, stream);
    deg_kernel_f<<<eblk256, 256, 0, stream>>>(src, dst, norm_src, norm_dst, E);
    norm_kernel_f<<<(2 * N + 255) / 256, 256, 0, stream>>>(norm_src, 2 * N);

    gemm_kernel<NFEAT_IN, false><<<nblk4, 256, 0, stream>>>(features, norm_src, W1, nullptr, bufA, N);
    hipMemsetAsync(bufB, 0, sizeof(float) * tot, stream);
    scatter_kernel<<<eblk, 256, 0, stream>>>(bufA, src, dst, bufB, E);
    hipMemsetAsync(stats, 0, sizeof(float) * 128, stream);
    elu_stats_kernel<<<2048, 256, 0, stream>>>(bufB, norm_dst, b1, stats, N);
    bn_finalize<<<1, 64, 0, stream>>>(stats, gamma1, beta1, coef, inv_n);
    bn_apply<<<tblk, 256, 0, stream>>>(bufB, coef, bufA, tot);

    gemm_kernel<NFEAT_H, false><<<nblk4, 256, 0, stream>>>(bufA, norm_src, W2, nullptr, bufB, N);
    hipMemsetAsync(bufA, 0, sizeof(float) * tot, stream);
    scatter_kernel<<<eblk, 256, 0, stream>>>(bufB, src, dst, bufA, E);
    hipMemsetAsync(stats, 0, sizeof(float) * 128, stream);
    elu_stats_kernel<<<2048, 256, 0, stream>>>(bufA, norm_dst, b2, stats, N);
    bn_finalize<<<1, 64, 0, stream>>>(stats, gamma2, beta2, coef, inv_n);
    bn_apply<<<tblk, 256, 0, stream>>>(bufA, coef, (float*)d_out, tot);
}